// Round 8
// baseline (215.698 us; speedup 1.0000x reference)
//
#include <hip/hip_runtime.h>
#include <stdint.h>

// Problem constants: B=4, C=256, H=W=64 -> HW=4096, vis=1024
#define B_   4
#define C_   256
#define HW_  4096
#define VIS_ 1024
#define KE2  512      // dedup f16 split: [hi(256) | lo(256)] per side

using half8   = __attribute__((ext_vector_type(8))) _Float16;
using floatx4 = __attribute__((ext_vector_type(4))) float;

__device__ __forceinline__ unsigned mapf(float v) {
    unsigned u = __float_as_uint(v);
    return (u & 0x80000000u) ? ~u : (u | 0x80000000u);
}

__global__ void init_ws_kernel(unsigned long long* ws, int n) {
    int i = blockIdx.x * blockDim.x + threadIdx.x;
    if (i < n) ws[i] = 0ull;
}

__global__ void finalize_kernel(const unsigned long long* __restrict__ ws,
                                float* __restrict__ out1, int n) {
    int i = blockIdx.x * blockDim.x + threadIdx.x;
    if (i < n) {
        unsigned kinv = (unsigned)(ws[i] & 0xFFFFFFFFull);
        out1[i] = (float)(HW_ - 1 - (int)kinv);
    }
}

// ---------------- f16-split MFMA path ----------------

// Transpose + split: src[b][c][hw] fp32 -> dst[b][hw][512] f16 = [hi | lo].
// Also zeroes the keys workspace.
__global__ __launch_bounds__(256) void split_transpose_kernel(
    const float* __restrict__ Q, const float* __restrict__ K,
    _Float16* __restrict__ Aexp, _Float16* __restrict__ Bexp,
    unsigned long long* __restrict__ keys)
{
    __shared__ float tile[64][65];   // [c][hw], pad 65 to break 8-col bank aliasing
    const int t = threadIdx.x;
    if (blockIdx.y == 0 && blockIdx.z == 0)
        keys[blockIdx.x * 256 + t] = 0ull;   // 64 blocks x 256 thr = 16384 = B_*HW_

    const int hw0 = blockIdx.x * 64;
    const int c0  = blockIdx.y * 64;
    const int z = blockIdx.z, b = z >> 1, which = z & 1;
    const float* src = (which ? K : Q) + (size_t)b * C_ * HW_;
    _Float16* dst = (which ? Bexp : Aexp) + (size_t)b * HW_ * KE2;

    #pragma unroll
    for (int i = 0; i < 4; ++i) {
        int c  = (t >> 4) + i * 16;
        int hw = (t & 15) * 4;
        float4 v = *(const float4*)(src + (size_t)(c0 + c) * HW_ + hw0 + hw);
        tile[c][hw] = v.x; tile[c][hw+1] = v.y; tile[c][hw+2] = v.z; tile[c][hw+3] = v.w;
    }
    __syncthreads();

    #pragma unroll
    for (int i = 0; i < 2; ++i) {
        int id  = t + i * 256;       // 0..511
        int row = id >> 3;           // hw within tile
        int c8  = (id & 7) * 8;      // c offset within 64
        half8 h8, l8;
        #pragma unroll
        for (int j = 0; j < 8; ++j) {
            float v = tile[c8 + j][row];
            _Float16 h = (_Float16)v;
            h8[j] = h;
            l8[j] = (_Float16)(v - (float)h);
        }
        _Float16* base = dst + (size_t)(hw0 + row) * KE2 + c0 + c8;
        *(half8*)(base + 0 * C_) = h8;   // hi segment
        *(half8*)(base + 1 * C_) = l8;   // lo segment
    }
}

__device__ __forceinline__ void gl2lds16(const _Float16* g, _Float16* l) {
    __builtin_amdgcn_global_load_lds(
        (const __attribute__((address_space(1))) void*)g,
        (__attribute__((address_space(3))) void*)l, 16, 0, 0);
}

// ---- 128x128 dedup-split GEMM, 2 blocks/CU for TLP pipe overlap ----
//
// Round-8 theory: rounds 2/5/6/7 were invariant at ~129 us because ONE
// barrier-locked 8-wave block per CU serializes the DS / MFMA / VALU / DMA
// pipes (serial pipe-sum ~280k cyc/CU matches measured 308k). Fix: 128x128
// tile, 4 waves, 64 KB LDS -> TWO independent blocks co-resident per CU;
// block A's ds_read/stage/epilogue overlap block B's MFMA (m114 mechanism).
// Chunk schedule, dedup reg-reuse combos, swizzles, VMC(8) pattern, and
// numerics are carried over from round 7 unchanged.
//
// LDS: 8 regions x 8 KB (region = p*4 + {0:Ah,1:Al,2:Bh,3:Bl}, p = c&1),
// 64 KB total. Boundary after chunk c: LGKM0+BARRIER (reads of buffer p
// done) -> stage chunk c+2 into p -> VMC(8) (chunk c+1 landed; c+2's 8
// outstanding) -> BARRIER.
// Chunk swizzle (involution on 16B chunks within a 64B row):
//   lds chunk (row, ch) holds global chunk ch ^ ((row>>1)&3)

#define BARRIER __builtin_amdgcn_s_barrier()
#define LGKM0   asm volatile("s_waitcnt lgkmcnt(0)" ::: "memory")
#define VMC(n)  asm volatile("s_waitcnt vmcnt(" #n ")" ::: "memory")
#define SCHEDB  __builtin_amdgcn_sched_barrier(0)

// one 128x32 half-panel: 512 chunks of 16B; 2 gl_lds per thread (256 thr).
// LDS dest linear in lane order (gl_lds requirement); global src inverse-
// swizzled so the read-side XOR sees data in place (rule 21).
__device__ __forceinline__ void stage_half(const _Float16* __restrict__ g,
                                           _Float16* lb, int t, int kbase)
{
    #pragma unroll
    for (int j = 0; j < 2; ++j) {
        const int c   = t + j * 256;
        const int row = c >> 2;          // 0..127
        const int ch  = (c & 3) ^ ((row >> 1) & 3);
        gl2lds16(g + (size_t)row * KE2 + kbase + ch * 8, lb + c * 8);
    }
}

// stage one chunk c into buffer p: Ah,Al,Bh,Bl = 8 gl_lds per thread
__device__ __forceinline__ void stage_chunk(const _Float16* __restrict__ Agl,
                                            const _Float16* __restrict__ Bgl,
                                            _Float16* lds, int p, int c, int t)
{
    stage_half(Agl, lds + (p * 4 + 0) * 4096, t, c * 32);         // Ah
    stage_half(Agl, lds + (p * 4 + 1) * 4096, t, 256 + c * 32);   // Al
    stage_half(Bgl, lds + (p * 4 + 2) * 4096, t, c * 32);         // Bh
    stage_half(Bgl, lds + (p * 4 + 3) * 4096, t, 256 + c * 32);   // Bl
}

__device__ __forceinline__ void ds_load_a(const _Float16* base, int wave_m, int s,
                                          int quad, half8 (&a)[4]) {
    #pragma unroll
    for (int mi = 0; mi < 4; ++mi) {
        int row = wave_m * 64 + mi * 16 + s;        // 0..127
        int ch  = quad ^ ((row >> 1) & 3);
        a[mi] = *(const half8*)(base + row * 32 + ch * 8);
    }
}

__device__ __forceinline__ void ds_load_b(const _Float16* base, int wave_n, int s,
                                          int quad, half8 (&bfr)[4]) {
    #pragma unroll
    for (int ni = 0; ni < 4; ++ni) {
        int col = wave_n * 64 + ni * 16 + s;        // 0..127
        int ch  = quad ^ ((col >> 1) & 3);
        bfr[ni] = *(const half8*)(base + col * 32 + ch * 8);
    }
}

__device__ __forceinline__ void do_mfma(const half8 (&a)[4], const half8 (&bfr)[4],
                                        floatx4 (&acc)[4][4]) {
    __builtin_amdgcn_s_setprio(1);
    #pragma unroll
    for (int mi = 0; mi < 4; ++mi)
        #pragma unroll
        for (int ni = 0; ni < 4; ++ni)
            acc[mi][ni] = __builtin_amdgcn_mfma_f32_16x16x32_f16(
                a[mi], bfr[ni], acc[mi][ni], 0, 0, 0);
    __builtin_amdgcn_s_setprio(0);
}

// one chunk: 16 ds_read_b128, 48 MFMA per wave; hi-fragments reused.
// Same summand set and order as round 7 (numerics identical).
__device__ __forceinline__ void chunk_compute(const _Float16* lds, int p,
    int wave_m, int wave_n, int s, int quad, floatx4 (&acc)[4][4])
{
    const _Float16* Ah = lds + (p * 4 + 0) * 4096;
    const _Float16* Al = lds + (p * 4 + 1) * 4096;
    const _Float16* Bh = lds + (p * 4 + 2) * 4096;
    const _Float16* Bl = lds + (p * 4 + 3) * 4096;
    half8 ah[4], x[4], bh[4];
    ds_load_a(Ah, wave_m, s, quad, ah);
    ds_load_b(Bh, wave_n, s, quad, bh);
    do_mfma(ah, bh, acc);             // ah * bh
    ds_load_b(Bl, wave_n, s, quad, x);
    do_mfma(ah, x, acc);              // ah * bl
    ds_load_a(Al, wave_m, s, quad, x);
    do_mfma(x, bh, acc);              // al * bh
}

__global__ __launch_bounds__(256, 2) void gemm_mfma_kernel(
    const _Float16* __restrict__ Aexp, const _Float16* __restrict__ Bexp,
    float* __restrict__ out0, unsigned long long* __restrict__ keys)
{
    __shared__ __align__(16) _Float16 lds[32768];   // 64 KiB = 8 regions x 8 KB

    const int t      = threadIdx.x;
    const int lane   = t & 63;
    const int wave   = t >> 6;        // 0..3
    const int quad   = lane >> 4;
    const int s      = lane & 15;
    const int wave_m = wave >> 1;     // 0..1 -> 64 output rows
    const int wave_n = wave & 1;      // 0..1 -> 64 output cols

    // T1: XCD-bijective swizzle (4096 % 8 == 0 -> exact chunks of 512).
    const int n    = blockIdx.x;
    const int wgid = (n & 7) * 512 + (n >> 3);
    const int kt   = wgid & 31;
    const int qt   = (wgid >> 5) & 31;
    const int b    = wgid >> 10;

    const _Float16* Agl = Aexp + (size_t)b * HW_ * KE2 + (size_t)(qt * 128) * KE2;
    const _Float16* Bgl = Bexp + (size_t)b * HW_ * KE2 + (size_t)(kt * 128) * KE2;

    // Prologue: stage chunks 0 (p0) and 1 (p1); VMC(8) forces chunk 0 landed.
    stage_chunk(Agl, Bgl, lds, 0, 0, t);
    stage_chunk(Agl, Bgl, lds, 1, 1, t);
    VMC(8);
    BARRIER; SCHEDB;

    floatx4 acc[4][4] = {};

    // Chunks 0..5: compute c, then boundary {reads-done barrier, stage c+2
    // into c's buffer, VMC(8) -> c+1 landed, barrier}.
    #pragma unroll 1
    for (int c = 0; c < 6; ++c) {
        chunk_compute(lds, c & 1, wave_m, wave_n, s, quad, acc);
        LGKM0;
        BARRIER;
        stage_chunk(Agl, Bgl, lds, c & 1, c + 2, t);
        VMC(8);
        BARRIER; SCHEDB;
    }
    // Chunk 6 (p0); then drain chunk 7's loads.
    chunk_compute(lds, 0, wave_m, wave_n, s, quad, acc);
    LGKM0;
    BARRIER;
    VMC(0);
    BARRIER; SCHEDB;
    // Chunk 7 (p1); LDS read-only from here.
    chunk_compute(lds, 1, wave_m, wave_n, s, quad, acc);

    // ---- Epilogue 1: S_vis corner (C/D layout: col=s, row=quad*4+r) ----
    if (qt < 8 && kt < 8) {
        #pragma unroll
        for (int mi = 0; mi < 4; ++mi)
            #pragma unroll
            for (int r = 0; r < 4; ++r) {
                int grow = qt * 128 + wave_m * 64 + mi * 16 + quad * 4 + r;
                float* orow = out0 + ((size_t)b * VIS_ + grow) * VIS_ + kt * 128 + wave_n * 64;
                #pragma unroll
                for (int ni = 0; ni < 4; ++ni)
                    orow[ni * 16 + s] = acc[mi][ni][r];
            }
    }

    // ---- Epilogue 2: fused argmax; alias reduction array onto staging LDS ----
    __syncthreads();
    unsigned long long* red = (unsigned long long*)lds;   // [128 rows][2 wave_n]

    #pragma unroll
    for (int mi = 0; mi < 4; ++mi) {
        #pragma unroll
        for (int r = 0; r < 4; ++r) {
            float best = acc[mi][0][r];
            int bcol = wave_n * 64 + s;
            #pragma unroll
            for (int ni = 1; ni < 4; ++ni) {
                float v = acc[mi][ni][r];
                if (v > best) { best = v; bcol = wave_n * 64 + ni * 16 + s; }
            }
            int gcol = kt * 128 + bcol;
            unsigned long long key = ((unsigned long long)mapf(best) << 32)
                                   | (unsigned)(HW_ - 1 - gcol);
            #pragma unroll
            for (int m = 1; m < 16; m <<= 1) {
                unsigned long long o = __shfl_xor(key, m, 64);
                if (o > key) key = o;
            }
            if (s == 0)
                red[(wave_m * 64 + mi * 16 + quad * 4 + r) * 2 + wave_n] = key;
        }
    }
    __syncthreads();
    if (t < 128) {
        unsigned long long k0 = red[t * 2 + 0], k1 = red[t * 2 + 1];
        atomicMax(&keys[(size_t)b * HW_ + qt * 128 + t], k0 > k1 ? k0 : k1);
    }
}

// ---------------- fp32 fallback path (round-1, known-good) ----------------
#define BT   64
#define BK   32
#define LDP  68

__global__ __launch_bounds__(256) void gemm_argmax_kernel(
    const float* __restrict__ Q, const float* __restrict__ K,
    float* __restrict__ out0, unsigned long long* __restrict__ ws)
{
    __shared__ float As[BK][LDP];
    __shared__ float Bs[BK][LDP];
    __shared__ unsigned long long red[BT][17];

    const int t  = threadIdx.x;
    const int tx = t & 15;
    const int ty = t >> 4;
    const int k0 = blockIdx.x * BT;
    const int q0 = blockIdx.y * BT;
    const int b  = blockIdx.z;

    const float* Qb = Q + (size_t)b * C_ * HW_;
    const float* Kb = K + (size_t)b * C_ * HW_;

    float acc[4][4] = {{0.f},{0.f},{0.f},{0.f}};

    for (int c0 = 0; c0 < C_; c0 += BK) {
        #pragma unroll
        for (int i = 0; i < 2; ++i) {
            int idx = i * 256 + t;
            int row = idx >> 4;
            int col = (idx & 15) * 4;
            const float4 a  = *(const float4*)(Qb + (size_t)(c0 + row) * HW_ + q0 + col);
            const float4 bv = *(const float4*)(Kb + (size_t)(c0 + row) * HW_ + k0 + col);
            *(float4*)(&As[row][col]) = a;
            *(float4*)(&Bs[row][col]) = bv;
        }
        __syncthreads();
        #pragma unroll
        for (int cc = 0; cc < BK; ++cc) {
            const float4 av = *(const float4*)(&As[cc][ty * 4]);
            const float4 bv = *(const float4*)(&Bs[cc][tx * 4]);
            const float a_[4] = {av.x, av.y, av.z, av.w};
            const float b_[4] = {bv.x, bv.y, bv.z, bv.w};
            #pragma unroll
            for (int i = 0; i < 4; ++i)
                #pragma unroll
                for (int j = 0; j < 4; ++j)
                    acc[i][j] = fmaf(a_[i], b_[j], acc[i][j]);
        }
        __syncthreads();
    }

    if (q0 < VIS_ && k0 < VIS_) {
        #pragma unroll
        for (int i = 0; i < 4; ++i) {
            float4 v = make_float4(acc[i][0], acc[i][1], acc[i][2], acc[i][3]);
            size_t off = (size_t)b * VIS_ * VIS_ + (size_t)(q0 + ty * 4 + i) * VIS_ + (k0 + tx * 4);
            *(float4*)(out0 + off) = v;
        }
    }

    #pragma unroll
    for (int i = 0; i < 4; ++i) {
        float best = acc[i][0];
        int   bj   = 0;
        #pragma unroll
        for (int j = 1; j < 4; ++j)
            if (acc[i][j] > best) { best = acc[i][j]; bj = j; }
        int kidx = k0 + tx * 4 + bj;
        unsigned long long key = ((unsigned long long)mapf(best) << 32)
                               | (unsigned)(HW_ - 1 - kidx);
        red[ty * 4 + i][tx] = key;
    }
    __syncthreads();
    if (t < BT) {
        unsigned long long best = red[t][0];
        #pragma unroll
        for (int j = 1; j < 16; ++j) {
            unsigned long long v = red[t][j];
            if (v > best) best = v;
        }
        atomicMax(&ws[(size_t)b * HW_ + q0 + t], best);
    }
}

extern "C" void kernel_launch(void* const* d_in, const int* in_sizes, int n_in,
                              void* d_out, int out_size, void* d_ws, size_t ws_size,
                              hipStream_t stream) {
    const float* Q = (const float*)d_in[0];
    const float* K = (const float*)d_in[1];
    float* out0 = (float*)d_out;
    float* out1 = out0 + (size_t)B_ * VIS_ * VIS_;

    unsigned long long* keys = (unsigned long long*)d_ws;     // 128 KB
    const size_t keys_bytes = (size_t)B_ * HW_ * 8;
    const size_t exp_elems  = (size_t)B_ * HW_ * KE2;
    const size_t need = keys_bytes + 2 * exp_elems * sizeof(_Float16);

    const int n = B_ * HW_;

    if (ws_size >= need) {
        _Float16* Aexp = (_Float16*)((char*)d_ws + keys_bytes);
        _Float16* Bexp = Aexp + exp_elems;
        split_transpose_kernel<<<dim3(HW_ / 64, C_ / 64, 2 * B_), 256, 0, stream>>>(Q, K, Aexp, Bexp, keys);
        gemm_mfma_kernel<<<dim3((HW_ / 128) * (HW_ / 128) * B_), 256, 0, stream>>>(Aexp, Bexp, out0, keys);
    } else {
        init_ws_kernel<<<(n + 255) / 256, 256, 0, stream>>>(keys, n);
        gemm_argmax_kernel<<<dim3(HW_ / BT, HW_ / BT, B_), 256, 0, stream>>>(Q, K, out0, keys);
    }

    finalize_kernel<<<(n + 255) / 256, 256, 0, stream>>>(keys, out1, n);
}

// Round 9
// 208.997 us; speedup vs baseline: 1.0321x; 1.0321x over previous
//
#include <hip/hip_runtime.h>
#include <stdint.h>

// Problem constants: B=4, C=256, H=W=64 -> HW=4096, vis=1024
#define B_   4
#define C_   256
#define HW_  4096
#define VIS_ 1024
#define KE2  512      // dedup f16 split: [hi(256) | lo(256)] per side

using half8   = __attribute__((ext_vector_type(8))) _Float16;
using floatx4 = __attribute__((ext_vector_type(4))) float;

__device__ __forceinline__ unsigned mapf(float v) {
    unsigned u = __float_as_uint(v);
    return (u & 0x80000000u) ? ~u : (u | 0x80000000u);
}

__global__ void init_ws_kernel(unsigned long long* ws, int n) {
    int i = blockIdx.x * blockDim.x + threadIdx.x;
    if (i < n) ws[i] = 0ull;
}

__global__ void finalize_kernel(const unsigned long long* __restrict__ ws,
                                float* __restrict__ out1, int n) {
    int i = blockIdx.x * blockDim.x + threadIdx.x;
    if (i < n) {
        unsigned kinv = (unsigned)(ws[i] & 0xFFFFFFFFull);
        out1[i] = (float)(HW_ - 1 - (int)kinv);
    }
}

// ---------------- f16-split MFMA path ----------------

// Round-9 rewrite: full-row streaming writes. Each block owns 32 hw-rows x
// all 256 c. Per c-chunk (64 c): coalesced fp32 loads -> in_tile -> cvt ->
// b128 writes into a [32][512] f16 out_tile. Final write-out: each wave
// stores ONE complete 1024-B output row per instruction (64 lanes x 16 B
// contiguous) - vs the old kernel's scattered 128-B segments. Output layout
// identical to round 7: dst[b][hw][512] = [hi(256) | lo(256)]. Also zeroes
// the keys workspace (blocks y==0,z==0).
__global__ __launch_bounds__(256) void split_transpose_kernel(
    const float* __restrict__ Q, const float* __restrict__ K,
    _Float16* __restrict__ Aexp, _Float16* __restrict__ Bexp,
    unsigned long long* __restrict__ keys)
{
    __shared__ float    in_tile[64][33];     // [c][hw], pad 33: <=2-way banks
    __shared__ _Float16 out_tile[32][512];   // [hw][hi|lo], full-BW b128 IO

    const int t = threadIdx.x;
    if (blockIdx.x < 64 && blockIdx.y == 0 && blockIdx.z == 0)
        keys[blockIdx.x * 256 + t] = 0ull;   // 64 blocks x 256 thr = B_*HW_

    const int hw0   = blockIdx.x * 32;
    const int which = blockIdx.y, b = blockIdx.z;
    const float* src = (which ? K : Q) + (size_t)b * C_ * HW_;
    _Float16*    dst = (which ? Bexp : Aexp) + (size_t)b * HW_ * KE2;

    #pragma unroll
    for (int cc = 0; cc < 4; ++cc) {
        const int c0 = cc * 64;
        // load [64 c][32 hw] fp32, coalesced float4
        #pragma unroll
        for (int i = 0; i < 2; ++i) {
            int c   = (t >> 3) + i * 32;
            int hw4 = (t & 7) * 4;
            float4 v = *(const float4*)(src + (size_t)(c0 + c) * HW_ + hw0 + hw4);
            in_tile[c][hw4] = v.x; in_tile[c][hw4+1] = v.y;
            in_tile[c][hw4+2] = v.z; in_tile[c][hw4+3] = v.w;
        }
        __syncthreads();
        // convert: thread (row = t>>3, c8 = (t&7)*8) -> hi/lo half8
        {
            int row = t >> 3;            // 0..31
            int c8  = (t & 7) * 8;       // 0..56
            half8 h8, l8;
            #pragma unroll
            for (int j = 0; j < 8; ++j) {
                float v = in_tile[c8 + j][row];
                _Float16 h = (_Float16)v;
                h8[j] = h;
                l8[j] = (_Float16)(v - (float)h);
            }
            *(half8*)&out_tile[row][c0 + c8]       = h8;
            *(half8*)&out_tile[row][256 + c0 + c8] = l8;
        }
        __syncthreads();                 // protect in_tile before next chunk
    }

    // write-out: 8 iterations, each wave stores one full 1-KB row
    #pragma unroll
    for (int it = 0; it < 8; ++it) {
        int row = it * 4 + (t >> 6);     // 0..31
        int col = (t & 63) * 8;          // f16 offset 0..504
        half8 v = *(const half8*)&out_tile[row][col];
        *(half8*)(dst + (size_t)(hw0 + row) * KE2 + col) = v;
    }
}

__device__ __forceinline__ void gl2lds16(const _Float16* g, _Float16* l) {
    __builtin_amdgcn_global_load_lds(
        (const __attribute__((address_space(1))) void*)g,
        (__attribute__((address_space(3))) void*)l, 16, 0, 0);
}

// ---- 256x256 dedup-split GEMM (round-7 revert: best measured, 128.6 us) ----
//
// 8 chunks of real-k=32; per chunk stage {Ah,Al,Bh,Bl} and compute
// ah*bh + ah*bl + al*bh with hi fragments reused in registers.
// LDS: 8 regions x 16 KB (region = p*4 + {0:Ah,1:Al,2:Bh,3:Bl}, p = c&1).
// Boundary after chunk c: LGKM0+BARRIER -> stage chunk c+2 into p ->
// VMC(8) (chunk c+1 landed) -> BARRIER.
// Chunk swizzle (involution on 16B chunks within a 64B row):
//   lds chunk (row, ch) holds global chunk ch ^ ((row>>1)&3)

#define BARRIER __builtin_amdgcn_s_barrier()
#define LGKM0   asm volatile("s_waitcnt lgkmcnt(0)" ::: "memory")
#define VMC(n)  asm volatile("s_waitcnt vmcnt(" #n ")" ::: "memory")
#define SCHEDB  __builtin_amdgcn_sched_barrier(0)

__device__ __forceinline__ void stage_half(const _Float16* __restrict__ g,
                                           _Float16* lb, int t, int kbase)
{
    #pragma unroll
    for (int j = 0; j < 2; ++j) {
        const int c   = t + j * 512;
        const int row = c >> 2;
        const int ch  = (c & 3) ^ ((row >> 1) & 3);
        gl2lds16(g + (size_t)row * KE2 + kbase + ch * 8, lb + c * 8);
    }
}

__device__ __forceinline__ void stage_chunk(const _Float16* __restrict__ Agl,
                                            const _Float16* __restrict__ Bgl,
                                            _Float16* lds, int p, int c, int t)
{
    stage_half(Agl, lds + (p * 4 + 0) * 8192, t, c * 32);         // Ah
    stage_half(Agl, lds + (p * 4 + 1) * 8192, t, 256 + c * 32);   // Al
    stage_half(Bgl, lds + (p * 4 + 2) * 8192, t, c * 32);         // Bh
    stage_half(Bgl, lds + (p * 4 + 3) * 8192, t, 256 + c * 32);   // Bl
}

template<int MQ>
__device__ __forceinline__ void ds_load_a(const _Float16* base, int wave_m, int s,
                                          int quad, half8 (&a)[4]) {
    #pragma unroll
    for (int mi = 0; mi < 4; ++mi) {
        int row = wave_m * 128 + MQ * 64 + mi * 16 + s;
        int ch  = quad ^ ((row >> 1) & 3);
        a[mi] = *(const half8*)(base + row * 32 + ch * 8);
    }
}

__device__ __forceinline__ void ds_load_b(const _Float16* base, int wave_n, int s,
                                          int quad, half8 (&bfr)[4]) {
    #pragma unroll
    for (int ni = 0; ni < 4; ++ni) {
        int col = wave_n * 64 + ni * 16 + s;
        int ch  = quad ^ ((col >> 1) & 3);
        bfr[ni] = *(const half8*)(base + col * 32 + ch * 8);
    }
}

template<int MQ>
__device__ __forceinline__ void do_mfma(const half8 (&a)[4], const half8 (&bfr)[4],
                                        floatx4 (&acc)[8][4]) {
    __builtin_amdgcn_s_setprio(1);
    #pragma unroll
    for (int mi = 0; mi < 4; ++mi)
        #pragma unroll
        for (int ni = 0; ni < 4; ++ni)
            acc[MQ * 4 + mi][ni] = __builtin_amdgcn_mfma_f32_16x16x32_f16(
                a[mi], bfr[ni], acc[MQ * 4 + mi][ni], 0, 0, 0);
    __builtin_amdgcn_s_setprio(0);
}

__device__ __forceinline__ void chunk_compute(const _Float16* lds, int p,
    int wave_m, int wave_n, int s, int quad, floatx4 (&acc)[8][4])
{
    const _Float16* Ah = lds + (p * 4 + 0) * 8192;
    const _Float16* Al = lds + (p * 4 + 1) * 8192;
    const _Float16* Bh = lds + (p * 4 + 2) * 8192;
    const _Float16* Bl = lds + (p * 4 + 3) * 8192;
    half8 a0[4], a1[4], bh[4], bl[4];
    ds_load_a<0>(Ah, wave_m, s, quad, a0);
    ds_load_a<1>(Ah, wave_m, s, quad, a1);
    ds_load_b(Bh, wave_n, s, quad, bh);
    do_mfma<0>(a0, bh, acc);          // ah * bh
    do_mfma<1>(a1, bh, acc);
    ds_load_b(Bl, wave_n, s, quad, bl);
    do_mfma<0>(a0, bl, acc);          // ah * bl
    do_mfma<1>(a1, bl, acc);
    ds_load_a<0>(Al, wave_m, s, quad, a0);
    ds_load_a<1>(Al, wave_m, s, quad, a1);
    do_mfma<0>(a0, bh, acc);          // al * bh
    do_mfma<1>(a1, bh, acc);
}

__global__ __launch_bounds__(512, 2) void gemm_mfma_kernel(
    const _Float16* __restrict__ Aexp, const _Float16* __restrict__ Bexp,
    float* __restrict__ out0, unsigned long long* __restrict__ keys)
{
    __shared__ __align__(16) _Float16 lds[65536];   // 128 KiB = 8 regions x 16 KB

    const int t      = threadIdx.x;
    const int lane   = t & 63;
    const int wave   = t >> 6;
    const int quad   = lane >> 4;
    const int s      = lane & 15;
    const int wave_m = wave >> 2;     // 0..1 -> 128 output rows
    const int wave_n = wave & 3;      // 0..3 -> 64 output cols

    // T1: XCD-bijective swizzle.
    const int n    = blockIdx.x;
    const int wgid = (n & 7) * 128 + (n >> 3);
    const int kt   = wgid & 15;
    const int qt   = (wgid >> 4) & 15;
    const int b    = wgid >> 8;

    const _Float16* Agl = Aexp + (size_t)b * HW_ * KE2 + (size_t)(qt * 256) * KE2;
    const _Float16* Bgl = Bexp + (size_t)b * HW_ * KE2 + (size_t)(kt * 256) * KE2;

    // Prologue: stage chunks 0 (p0) and 1 (p1); VMC(8) forces chunk 0 landed.
    stage_chunk(Agl, Bgl, lds, 0, 0, t);
    stage_chunk(Agl, Bgl, lds, 1, 1, t);
    VMC(8);
    BARRIER; SCHEDB;

    floatx4 acc[8][4] = {};

    #pragma unroll 1
    for (int c = 0; c < 6; ++c) {
        chunk_compute(lds, c & 1, wave_m, wave_n, s, quad, acc);
        LGKM0;
        BARRIER;
        stage_chunk(Agl, Bgl, lds, c & 1, c + 2, t);
        VMC(8);
        BARRIER; SCHEDB;
    }
    chunk_compute(lds, 0, wave_m, wave_n, s, quad, acc);
    LGKM0;
    BARRIER;
    VMC(0);
    BARRIER; SCHEDB;
    chunk_compute(lds, 1, wave_m, wave_n, s, quad, acc);

    // ---- Epilogue 1: S_vis corner (C/D layout: col=s, row=quad*4+r) ----
    if (qt < 4 && kt < 4) {
        #pragma unroll
        for (int mi8 = 0; mi8 < 8; ++mi8)
            #pragma unroll
            for (int r = 0; r < 4; ++r) {
                int grow = qt * 256 + wave_m * 128 + mi8 * 16 + quad * 4 + r;
                float* orow = out0 + ((size_t)b * VIS_ + grow) * VIS_ + kt * 256 + wave_n * 64;
                #pragma unroll
                for (int ni = 0; ni < 4; ++ni)
                    orow[ni * 16 + s] = acc[mi8][ni][r];
            }
    }

    // ---- Epilogue 2: fused argmax; alias reduction array onto staging LDS ----
    __syncthreads();
    unsigned long long* red = (unsigned long long*)lds;   // [256 rows][4 wave_n]

    #pragma unroll
    for (int mi8 = 0; mi8 < 8; ++mi8) {
        #pragma unroll
        for (int r = 0; r < 4; ++r) {
            float best = acc[mi8][0][r];
            int bcol = wave_n * 64 + s;
            #pragma unroll
            for (int ni = 1; ni < 4; ++ni) {
                float v = acc[mi8][ni][r];
                if (v > best) { best = v; bcol = wave_n * 64 + ni * 16 + s; }
            }
            int gcol = kt * 256 + bcol;
            unsigned long long key = ((unsigned long long)mapf(best) << 32)
                                   | (unsigned)(HW_ - 1 - gcol);
            #pragma unroll
            for (int m = 1; m < 16; m <<= 1) {
                unsigned long long o = __shfl_xor(key, m, 64);
                if (o > key) key = o;
            }
            if (s == 0)
                red[(wave_m * 128 + mi8 * 16 + quad * 4 + r) * 4 + wave_n] = key;
        }
    }
    __syncthreads();
    if (t < 256) {
        const unsigned long long* rr = red + t * 4;
        unsigned long long k0 = rr[0], k1 = rr[1], k2 = rr[2], k3 = rr[3];
        unsigned long long m01 = k0 > k1 ? k0 : k1;
        unsigned long long m23 = k2 > k3 ? k2 : k3;
        atomicMax(&keys[(size_t)b * HW_ + qt * 256 + t], m01 > m23 ? m01 : m23);
    }
}

// ---------------- fp32 fallback path (round-1, known-good) ----------------
#define BT   64
#define BK   32
#define LDP  68

__global__ __launch_bounds__(256) void gemm_argmax_kernel(
    const float* __restrict__ Q, const float* __restrict__ K,
    float* __restrict__ out0, unsigned long long* __restrict__ ws)
{
    __shared__ float As[BK][LDP];
    __shared__ float Bs[BK][LDP];
    __shared__ unsigned long long red[BT][17];

    const int t  = threadIdx.x;
    const int tx = t & 15;
    const int ty = t >> 4;
    const int k0 = blockIdx.x * BT;
    const int q0 = blockIdx.y * BT;
    const int b  = blockIdx.z;

    const float* Qb = Q + (size_t)b * C_ * HW_;
    const float* Kb = K + (size_t)b * C_ * HW_;

    float acc[4][4] = {{0.f},{0.f},{0.f},{0.f}};

    for (int c0 = 0; c0 < C_; c0 += BK) {
        #pragma unroll
        for (int i = 0; i < 2; ++i) {
            int idx = i * 256 + t;
            int row = idx >> 4;
            int col = (idx & 15) * 4;
            const float4 a  = *(const float4*)(Qb + (size_t)(c0 + row) * HW_ + q0 + col);
            const float4 bv = *(const float4*)(Kb + (size_t)(c0 + row) * HW_ + k0 + col);
            *(float4*)(&As[row][col]) = a;
            *(float4*)(&Bs[row][col]) = bv;
        }
        __syncthreads();
        #pragma unroll
        for (int cc = 0; cc < BK; ++cc) {
            const float4 av = *(const float4*)(&As[cc][ty * 4]);
            const float4 bv = *(const float4*)(&Bs[cc][tx * 4]);
            const float a_[4] = {av.x, av.y, av.z, av.w};
            const float b_[4] = {bv.x, bv.y, bv.z, bv.w};
            #pragma unroll
            for (int i = 0; i < 4; ++i)
                #pragma unroll
                for (int j = 0; j < 4; ++j)
                    acc[i][j] = fmaf(a_[i], b_[j], acc[i][j]);
        }
        __syncthreads();
    }

    if (q0 < VIS_ && k0 < VIS_) {
        #pragma unroll
        for (int i = 0; i < 4; ++i) {
            float4 v = make_float4(acc[i][0], acc[i][1], acc[i][2], acc[i][3]);
            size_t off = (size_t)b * VIS_ * VIS_ + (size_t)(q0 + ty * 4 + i) * VIS_ + (k0 + tx * 4);
            *(float4*)(out0 + off) = v;
        }
    }

    #pragma unroll
    for (int i = 0; i < 4; ++i) {
        float best = acc[i][0];
        int   bj   = 0;
        #pragma unroll
        for (int j = 1; j < 4; ++j)
            if (acc[i][j] > best) { best = acc[i][j]; bj = j; }
        int kidx = k0 + tx * 4 + bj;
        unsigned long long key = ((unsigned long long)mapf(best) << 32)
                               | (unsigned)(HW_ - 1 - kidx);
        red[ty * 4 + i][tx] = key;
    }
    __syncthreads();
    if (t < BT) {
        unsigned long long best = red[t][0];
        #pragma unroll
        for (int j = 1; j < 16; ++j) {
            unsigned long long v = red[t][j];
            if (v > best) best = v;
        }
        atomicMax(&ws[(size_t)b * HW_ + q0 + t], best);
    }
}

extern "C" void kernel_launch(void* const* d_in, const int* in_sizes, int n_in,
                              void* d_out, int out_size, void* d_ws, size_t ws_size,
                              hipStream_t stream) {
    const float* Q = (const float*)d_in[0];
    const float* K = (const float*)d_in[1];
    float* out0 = (float*)d_out;
    float* out1 = out0 + (size_t)B_ * VIS_ * VIS_;

    unsigned long long* keys = (unsigned long long*)d_ws;     // 128 KB
    const size_t keys_bytes = (size_t)B_ * HW_ * 8;
    const size_t exp_elems  = (size_t)B_ * HW_ * KE2;
    const size_t need = keys_bytes + 2 * exp_elems * sizeof(_Float16);

    const int n = B_ * HW_;

    if (ws_size >= need) {
        _Float16* Aexp = (_Float16*)((char*)d_ws + keys_bytes);
        _Float16* Bexp = Aexp + exp_elems;
        split_transpose_kernel<<<dim3(HW_ / 32, 2, B_), 256, 0, stream>>>(Q, K, Aexp, Bexp, keys);
        gemm_mfma_kernel<<<dim3((HW_ / 256) * (HW_ / 256) * B_), 512, 0, stream>>>(Aexp, Bexp, out0, keys);
    } else {
        init_ws_kernel<<<(n + 255) / 256, 256, 0, stream>>>(keys, n);
        gemm_argmax_kernel<<<dim3(HW_ / BT, HW_ / BT, B_), 256, 0, stream>>>(Q, K, out0, keys);
    }

    finalize_kernel<<<(n + 255) / 256, 256, 0, stream>>>(keys, out1, n);
}

// Round 10
// 206.379 us; speedup vs baseline: 1.0452x; 1.0127x over previous
//
#include <hip/hip_runtime.h>
#include <stdint.h>

// Problem constants: B=4, C=256, H=W=64 -> HW=4096, vis=1024
#define B_   4
#define C_   256
#define HW_  4096
#define VIS_ 1024

using half8   = __attribute__((ext_vector_type(8))) _Float16;
using floatx4 = __attribute__((ext_vector_type(4))) float;

__device__ __forceinline__ unsigned mapf(float v) {
    unsigned u = __float_as_uint(v);
    return (u & 0x80000000u) ? ~u : (u | 0x80000000u);
}

__global__ void init_ws_kernel(unsigned long long* ws, int n) {
    int i = blockIdx.x * blockDim.x + threadIdx.x;
    if (i < n) ws[i] = 0ull;
}

__global__ void finalize_kernel(const unsigned long long* __restrict__ ws,
                                float* __restrict__ out1, int n) {
    int i = blockIdx.x * blockDim.x + threadIdx.x;
    if (i < n) {
        unsigned kinv = (unsigned)(ws[i] & 0xFFFFFFFFull);
        out1[i] = (float)(HW_ - 1 - (int)kinv);
    }
}

// ---- FUSED 256x256 dedup-split GEMM: reads fp32 Q/K directly ----
//
// Round-10 change: the 33.5 MB Aexp/Bexp intermediate is ELIMINATED.
// Cross-round accounting showed the split pipeline costs ~50-60 us
// (~5x its HBM roofline) regardless of its internal structure; a fp32
// panel row (256 x 4 B) equals the dedup f16 row (512 x 2 B) in bytes,
// so direct fp32 reads cost the same HBM traffic. Staging per chunk:
// 32 coalesced dword loads/thread issued ONE CHUNK AHEAD (latency hides
// under MFMA), fp32->hi/lo f16 convert in VALU, 8 ds_write_b128 into the
// same swizzled LDS layout as rounds 7/9. Per-element accumulation order
// (hi*hi, hi*lo, lo*hi) preserved -> numerics identical.
//
// LDS: 8 regions x 16 KB (region = p*4 + {0:Ah,1:Al,2:Bh,3:Bl}, p = c&1).
// Boundary after chunk c: LGKM0+BARRIER (reads of p done) -> cvt+write
// chunk c+2 into p (loads landed; compiler-tracked waits) -> issue loads
// for chunk c+3 -> LGKM0+BARRIER (writes visible). No vmcnt drains: raw
// barriers only (no __syncthreads in the loop).
// Chunk swizzle (involution on 16B chunks within a 64B row):
//   lds chunk (row, ch) holds global k-chunk ch ^ ((row>>1)&3)

#define BARRIER __builtin_amdgcn_s_barrier()
#define LGKM0   asm volatile("s_waitcnt lgkmcnt(0)" ::: "memory")
#define SCHEDB  __builtin_amdgcn_sched_barrier(0)

// Issue 32 dword loads for chunk at kb: unit (hw = t&255, oct = t>>8 + 2k),
// 8 c-consecutive dwords each; lanes have consecutive hw -> 256 B coalesced.
__device__ __forceinline__ void stage_load(const float* __restrict__ Qp,
                                           const float* __restrict__ Kp,
                                           int kb, int t,
                                           float (&ra)[2][8], float (&rb)[2][8])
{
    const int hw = t & 255, o0 = t >> 8;
    #pragma unroll
    for (int k = 0; k < 2; ++k) {
        const int c0 = kb + (o0 + 2 * k) * 8;
        const float* qa = Qp + (size_t)c0 * HW_ + hw;
        const float* ka = Kp + (size_t)c0 * HW_ + hw;
        #pragma unroll
        for (int j = 0; j < 8; ++j) {
            ra[k][j] = qa[(size_t)j * HW_];
            rb[k][j] = ka[(size_t)j * HW_];
        }
    }
}

// Convert held fp32 regs to hi/lo f16 and write into buffer p (swizzled).
__device__ __forceinline__ void cvt_write(_Float16* lds, int p, int t,
                                          const float (&ra)[2][8],
                                          const float (&rb)[2][8])
{
    _Float16* Ah = lds + (p * 4 + 0) * 8192;
    _Float16* Al = lds + (p * 4 + 1) * 8192;
    _Float16* Bh = lds + (p * 4 + 2) * 8192;
    _Float16* Bl = lds + (p * 4 + 3) * 8192;
    const int hw = t & 255, o0 = t >> 8, swz = (hw >> 1) & 3;
    #pragma unroll
    for (int k = 0; k < 2; ++k) {
        const int ch = (o0 + 2 * k) ^ swz;
        half8 ha, la, hb, lb;
        #pragma unroll
        for (int j = 0; j < 8; ++j) {
            float v = ra[k][j];
            _Float16 h = (_Float16)v;
            ha[j] = h; la[j] = (_Float16)(v - (float)h);
            float w = rb[k][j];
            _Float16 g = (_Float16)w;
            hb[j] = g; lb[j] = (_Float16)(w - (float)g);
        }
        *(half8*)(Ah + hw * 32 + ch * 8) = ha;
        *(half8*)(Al + hw * 32 + ch * 8) = la;
        *(half8*)(Bh + hw * 32 + ch * 8) = hb;
        *(half8*)(Bl + hw * 32 + ch * 8) = lb;
    }
}

template<int MQ>
__device__ __forceinline__ void ds_load_a(const _Float16* base, int wave_m, int s,
                                          int quad, half8 (&a)[4]) {
    #pragma unroll
    for (int mi = 0; mi < 4; ++mi) {
        int row = wave_m * 128 + MQ * 64 + mi * 16 + s;
        int ch  = quad ^ ((row >> 1) & 3);
        a[mi] = *(const half8*)(base + row * 32 + ch * 8);
    }
}

__device__ __forceinline__ void ds_load_b(const _Float16* base, int wave_n, int s,
                                          int quad, half8 (&bfr)[4]) {
    #pragma unroll
    for (int ni = 0; ni < 4; ++ni) {
        int col = wave_n * 64 + ni * 16 + s;
        int ch  = quad ^ ((col >> 1) & 3);
        bfr[ni] = *(const half8*)(base + col * 32 + ch * 8);
    }
}

template<int MQ>
__device__ __forceinline__ void do_mfma(const half8 (&a)[4], const half8 (&bfr)[4],
                                        floatx4 (&acc)[8][4]) {
    __builtin_amdgcn_s_setprio(1);
    #pragma unroll
    for (int mi = 0; mi < 4; ++mi)
        #pragma unroll
        for (int ni = 0; ni < 4; ++ni)
            acc[MQ * 4 + mi][ni] = __builtin_amdgcn_mfma_f32_16x16x32_f16(
                a[mi], bfr[ni], acc[MQ * 4 + mi][ni], 0, 0, 0);
    __builtin_amdgcn_s_setprio(0);
}

// One chunk: 24 ds_read_b128, 96 MFMA per wave. Single a-buffer (48-reg
// fragment peak) to fund the +32 staging registers. Per-element order:
// hi*hi, hi*lo, lo*hi — identical to rounds 7/9.
__device__ __forceinline__ void chunk_compute(const _Float16* lds, int p,
    int wave_m, int wave_n, int s, int quad, floatx4 (&acc)[8][4])
{
    const _Float16* Ah = lds + (p * 4 + 0) * 8192;
    const _Float16* Al = lds + (p * 4 + 1) * 8192;
    const _Float16* Bh = lds + (p * 4 + 2) * 8192;
    const _Float16* Bl = lds + (p * 4 + 3) * 8192;
    half8 bh[4], bl[4], a[4];
    ds_load_b(Bh, wave_n, s, quad, bh);
    ds_load_b(Bl, wave_n, s, quad, bl);
    ds_load_a<0>(Ah, wave_m, s, quad, a);
    do_mfma<0>(a, bh, acc);           // mq0: hi*hi
    do_mfma<0>(a, bl, acc);           // mq0: hi*lo
    ds_load_a<1>(Ah, wave_m, s, quad, a);
    do_mfma<1>(a, bh, acc);           // mq1: hi*hi
    do_mfma<1>(a, bl, acc);           // mq1: hi*lo
    ds_load_a<0>(Al, wave_m, s, quad, a);
    do_mfma<0>(a, bh, acc);           // mq0: lo*hi
    ds_load_a<1>(Al, wave_m, s, quad, a);
    do_mfma<1>(a, bh, acc);           // mq1: lo*hi
}

__global__ __launch_bounds__(512, 2) void gemm_mfma_kernel(
    const float* __restrict__ Q, const float* __restrict__ K,
    float* __restrict__ out0, unsigned long long* __restrict__ keys)
{
    __shared__ __align__(16) _Float16 lds[65536];   // 128 KiB = 8 regions x 16 KB

    const int t      = threadIdx.x;
    const int lane   = t & 63;
    const int wave   = t >> 6;
    const int quad   = lane >> 4;
    const int s      = lane & 15;
    const int wave_m = wave >> 2;     // 0..1 -> 128 output rows
    const int wave_n = wave & 3;      // 0..3 -> 64 output cols

    // T1: XCD-bijective swizzle.
    const int n    = blockIdx.x;
    const int wgid = (n & 7) * 128 + (n >> 3);
    const int kt   = wgid & 15;
    const int qt   = (wgid >> 4) & 15;
    const int b    = wgid >> 8;

    const float* Qp = Q + (size_t)b * C_ * HW_ + qt * 256;   // panel: [c][256 hw]
    const float* Kp = K + (size_t)b * C_ * HW_ + kt * 256;

    float ra[2][8], rb[2][8];

    // Prologue: stage chunks 0,1 synchronously; issue loads for chunk 2.
    stage_load(Qp, Kp, 0, t, ra, rb);
    cvt_write(lds, 0, t, ra, rb);
    stage_load(Qp, Kp, 32, t, ra, rb);
    cvt_write(lds, 1, t, ra, rb);
    stage_load(Qp, Kp, 64, t, ra, rb);
    LGKM0; BARRIER; SCHEDB;

    floatx4 acc[8][4] = {};

    // Chunks 0..5: compute c; boundary writes chunk c+2 (loads held in regs
    // since previous boundary) and issues loads for c+3.
    #pragma unroll 1
    for (int c = 0; c < 6; ++c) {
        chunk_compute(lds, c & 1, wave_m, wave_n, s, quad, acc);
        LGKM0; BARRIER;                 // all reads of buffer p done
        cvt_write(lds, c & 1, t, ra, rb);   // chunk c+2 -> p
        if (c < 5) stage_load(Qp, Kp, (c + 3) * 32, t, ra, rb);
        LGKM0; BARRIER; SCHEDB;         // writes visible
    }
    // Chunks 6,7: fully staged; LDS read-only from here.
    chunk_compute(lds, 0, wave_m, wave_n, s, quad, acc);
    chunk_compute(lds, 1, wave_m, wave_n, s, quad, acc);

    // ---- Epilogue 1: S_vis corner (C/D layout: col=s, row=quad*4+r) ----
    if (qt < 4 && kt < 4) {
        #pragma unroll
        for (int mi8 = 0; mi8 < 8; ++mi8)
            #pragma unroll
            for (int r = 0; r < 4; ++r) {
                int grow = qt * 256 + wave_m * 128 + mi8 * 16 + quad * 4 + r;
                float* orow = out0 + ((size_t)b * VIS_ + grow) * VIS_ + kt * 256 + wave_n * 64;
                #pragma unroll
                for (int ni = 0; ni < 4; ++ni)
                    orow[ni * 16 + s] = acc[mi8][ni][r];
            }
    }

    // ---- Epilogue 2: fused argmax; alias reduction array onto staging LDS ----
    __syncthreads();
    unsigned long long* red = (unsigned long long*)lds;   // [256 rows][4 wave_n]

    #pragma unroll
    for (int mi8 = 0; mi8 < 8; ++mi8) {
        #pragma unroll
        for (int r = 0; r < 4; ++r) {
            float best = acc[mi8][0][r];
            int bcol = wave_n * 64 + s;
            #pragma unroll
            for (int ni = 1; ni < 4; ++ni) {
                float v = acc[mi8][ni][r];
                if (v > best) { best = v; bcol = wave_n * 64 + ni * 16 + s; }
            }
            int gcol = kt * 256 + bcol;
            unsigned long long key = ((unsigned long long)mapf(best) << 32)
                                   | (unsigned)(HW_ - 1 - gcol);
            #pragma unroll
            for (int m = 1; m < 16; m <<= 1) {
                unsigned long long o = __shfl_xor(key, m, 64);
                if (o > key) key = o;
            }
            if (s == 0)
                red[(wave_m * 128 + mi8 * 16 + quad * 4 + r) * 4 + wave_n] = key;
        }
    }
    __syncthreads();
    if (t < 256) {
        const unsigned long long* rr = red + t * 4;
        unsigned long long k0 = rr[0], k1 = rr[1], k2 = rr[2], k3 = rr[3];
        unsigned long long m01 = k0 > k1 ? k0 : k1;
        unsigned long long m23 = k2 > k3 ? k2 : k3;
        atomicMax(&keys[(size_t)b * HW_ + qt * 256 + t], m01 > m23 ? m01 : m23);
    }
}

// ---------------- fp32 fallback path (round-1, known-good) ----------------
#define BT   64
#define BK   32
#define LDP  68

__global__ __launch_bounds__(256) void gemm_argmax_kernel(
    const float* __restrict__ Q, const float* __restrict__ K,
    float* __restrict__ out0, unsigned long long* __restrict__ ws)
{
    __shared__ float As[BK][LDP];
    __shared__ float Bs[BK][LDP];
    __shared__ unsigned long long red[BT][17];

    const int t  = threadIdx.x;
    const int tx = t & 15;
    const int ty = t >> 4;
    const int k0 = blockIdx.x * BT;
    const int q0 = blockIdx.y * BT;
    const int b  = blockIdx.z;

    const float* Qb = Q + (size_t)b * C_ * HW_;
    const float* Kb = K + (size_t)b * C_ * HW_;

    float acc[4][4] = {{0.f},{0.f},{0.f},{0.f}};

    for (int c0 = 0; c0 < C_; c0 += BK) {
        #pragma unroll
        for (int i = 0; i < 2; ++i) {
            int idx = i * 256 + t;
            int row = idx >> 4;
            int col = (idx & 15) * 4;
            const float4 a  = *(const float4*)(Qb + (size_t)(c0 + row) * HW_ + q0 + col);
            const float4 bv = *(const float4*)(Kb + (size_t)(c0 + row) * HW_ + k0 + col);
            *(float4*)(&As[row][col]) = a;
            *(float4*)(&Bs[row][col]) = bv;
        }
        __syncthreads();
        #pragma unroll
        for (int cc = 0; cc < BK; ++cc) {
            const float4 av = *(const float4*)(&As[cc][ty * 4]);
            const float4 bv = *(const float4*)(&Bs[cc][tx * 4]);
            const float a_[4] = {av.x, av.y, av.z, av.w};
            const float b_[4] = {bv.x, bv.y, bv.z, bv.w};
            #pragma unroll
            for (int i = 0; i < 4; ++i)
                #pragma unroll
                for (int j = 0; j < 4; ++j)
                    acc[i][j] = fmaf(a_[i], b_[j], acc[i][j]);
        }
        __syncthreads();
    }

    if (q0 < VIS_ && k0 < VIS_) {
        #pragma unroll
        for (int i = 0; i < 4; ++i) {
            float4 v = make_float4(acc[i][0], acc[i][1], acc[i][2], acc[i][3]);
            size_t off = (size_t)b * VIS_ * VIS_ + (size_t)(q0 + ty * 4 + i) * VIS_ + (k0 + tx * 4);
            *(float4*)(out0 + off) = v;
        }
    }

    #pragma unroll
    for (int i = 0; i < 4; ++i) {
        float best = acc[i][0];
        int   bj   = 0;
        #pragma unroll
        for (int j = 1; j < 4; ++j)
            if (acc[i][j] > best) { best = acc[i][j]; bj = j; }
        int kidx = k0 + tx * 4 + bj;
        unsigned long long key = ((unsigned long long)mapf(best) << 32)
                               | (unsigned)(HW_ - 1 - kidx);
        red[ty * 4 + i][tx] = key;
    }
    __syncthreads();
    if (t < BT) {
        unsigned long long best = red[t][0];
        #pragma unroll
        for (int j = 1; j < 16; ++j) {
            unsigned long long v = red[t][j];
            if (v > best) best = v;
        }
        atomicMax(&ws[(size_t)b * HW_ + q0 + t], best);
    }
}

extern "C" void kernel_launch(void* const* d_in, const int* in_sizes, int n_in,
                              void* d_out, int out_size, void* d_ws, size_t ws_size,
                              hipStream_t stream) {
    const float* Q = (const float*)d_in[0];
    const float* K = (const float*)d_in[1];
    float* out0 = (float*)d_out;
    float* out1 = out0 + (size_t)B_ * VIS_ * VIS_;

    unsigned long long* keys = (unsigned long long*)d_ws;     // 128 KB
    const size_t keys_bytes = (size_t)B_ * HW_ * 8;

    const int n = B_ * HW_;
    init_ws_kernel<<<(n + 255) / 256, 256, 0, stream>>>(keys, n);

    if (ws_size >= keys_bytes) {
        gemm_mfma_kernel<<<dim3((HW_ / 256) * (HW_ / 256) * B_), 512, 0, stream>>>(Q, K, out0, keys);
    } else {
        gemm_argmax_kernel<<<dim3(HW_ / BT, HW_ / BT, B_), 256, 0, stream>>>(Q, K, out0, keys);
    }

    finalize_kernel<<<(n + 255) / 256, 256, 0, stream>>>(keys, out1, n);
}

// Round 11
// 204.232 us; speedup vs baseline: 1.0561x; 1.0105x over previous
//
#include <hip/hip_runtime.h>
#include <stdint.h>

// Problem constants: B=4, C=256, H=W=64 -> HW=4096, vis=1024
#define B_   4
#define C_   256
#define HW_  4096
#define VIS_ 1024
#define NKT  16       // kt slices (HW_/256)

using half8   = __attribute__((ext_vector_type(8))) _Float16;
using floatx4 = __attribute__((ext_vector_type(4))) float;

__device__ __forceinline__ unsigned mapf(float v) {
    unsigned u = __float_as_uint(v);
    return (u & 0x80000000u) ? ~u : (u | 0x80000000u);
}

__global__ void init_ws_kernel(unsigned long long* ws, int n) {
    int i = blockIdx.x * blockDim.x + threadIdx.x;
    if (i < n) ws[i] = 0ull;
}

// Reduce `slices` partial key slices (each n rows) and emit argmax index.
__global__ void finalize_kernel(const unsigned long long* __restrict__ ws,
                                float* __restrict__ out1, int n, int slices) {
    int i = blockIdx.x * blockDim.x + threadIdx.x;
    if (i < n) {
        unsigned long long best = ws[i];
        for (int k = 1; k < slices; ++k) {
            unsigned long long v = ws[(size_t)k * n + i];
            if (v > best) best = v;
        }
        unsigned kinv = (unsigned)(best & 0xFFFFFFFFull);
        out1[i] = (float)(HW_ - 1 - (int)kinv);
    }
}

// ---- FUSED 256x256 dedup-split GEMM: reads fp32 Q/K directly ----
//
// Round-11 change: epilogue writes per-kt PARTIAL key slices with plain
// coalesced stores (keys_part[kt][row], each slot written exactly once) —
// no atomics, no workspace init -> init_ws launch deleted (main path is
// 2 launches). finalize reduces the 16 slices. GEMM loop unchanged from
// round 10 (fused fp32 staging, dedup hi/lo split in VALU, per-element
// accumulation order hi*hi, hi*lo, lo*hi).
//
// LDS: 8 regions x 16 KB (region = p*4 + {0:Ah,1:Al,2:Bh,3:Bl}, p = c&1).
// Boundary after chunk c: LGKM0+BARRIER (reads of p done) -> cvt+write
// chunk c+2 into p -> issue loads for chunk c+3 -> LGKM0+BARRIER.
// Chunk swizzle (involution on 16B chunks within a 64B row):
//   lds chunk (row, ch) holds global k-chunk ch ^ ((row>>1)&3)

#define BARRIER __builtin_amdgcn_s_barrier()
#define LGKM0   asm volatile("s_waitcnt lgkmcnt(0)" ::: "memory")
#define SCHEDB  __builtin_amdgcn_sched_barrier(0)

// Issue 32 dword loads for chunk at kb: unit (hw = t&255, oct = t>>8 + 2k),
// 8 c-consecutive dwords each; lanes have consecutive hw -> coalesced.
__device__ __forceinline__ void stage_load(const float* __restrict__ Qp,
                                           const float* __restrict__ Kp,
                                           int kb, int t,
                                           float (&ra)[2][8], float (&rb)[2][8])
{
    const int hw = t & 255, o0 = t >> 8;
    #pragma unroll
    for (int k = 0; k < 2; ++k) {
        const int c0 = kb + (o0 + 2 * k) * 8;
        const float* qa = Qp + (size_t)c0 * HW_ + hw;
        const float* ka = Kp + (size_t)c0 * HW_ + hw;
        #pragma unroll
        for (int j = 0; j < 8; ++j) {
            ra[k][j] = qa[(size_t)j * HW_];
            rb[k][j] = ka[(size_t)j * HW_];
        }
    }
}

// Convert held fp32 regs to hi/lo f16 and write into buffer p (swizzled).
__device__ __forceinline__ void cvt_write(_Float16* lds, int p, int t,
                                          const float (&ra)[2][8],
                                          const float (&rb)[2][8])
{
    _Float16* Ah = lds + (p * 4 + 0) * 8192;
    _Float16* Al = lds + (p * 4 + 1) * 8192;
    _Float16* Bh = lds + (p * 4 + 2) * 8192;
    _Float16* Bl = lds + (p * 4 + 3) * 8192;
    const int hw = t & 255, o0 = t >> 8, swz = (hw >> 1) & 3;
    #pragma unroll
    for (int k = 0; k < 2; ++k) {
        const int ch = (o0 + 2 * k) ^ swz;
        half8 ha, la, hb, lb;
        #pragma unroll
        for (int j = 0; j < 8; ++j) {
            float v = ra[k][j];
            _Float16 h = (_Float16)v;
            ha[j] = h; la[j] = (_Float16)(v - (float)h);
            float w = rb[k][j];
            _Float16 g = (_Float16)w;
            hb[j] = g; lb[j] = (_Float16)(w - (float)g);
        }
        *(half8*)(Ah + hw * 32 + ch * 8) = ha;
        *(half8*)(Al + hw * 32 + ch * 8) = la;
        *(half8*)(Bh + hw * 32 + ch * 8) = hb;
        *(half8*)(Bl + hw * 32 + ch * 8) = lb;
    }
}

template<int MQ>
__device__ __forceinline__ void ds_load_a(const _Float16* base, int wave_m, int s,
                                          int quad, half8 (&a)[4]) {
    #pragma unroll
    for (int mi = 0; mi < 4; ++mi) {
        int row = wave_m * 128 + MQ * 64 + mi * 16 + s;
        int ch  = quad ^ ((row >> 1) & 3);
        a[mi] = *(const half8*)(base + row * 32 + ch * 8);
    }
}

__device__ __forceinline__ void ds_load_b(const _Float16* base, int wave_n, int s,
                                          int quad, half8 (&bfr)[4]) {
    #pragma unroll
    for (int ni = 0; ni < 4; ++ni) {
        int col = wave_n * 64 + ni * 16 + s;
        int ch  = quad ^ ((col >> 1) & 3);
        bfr[ni] = *(const half8*)(base + col * 32 + ch * 8);
    }
}

template<int MQ>
__device__ __forceinline__ void do_mfma(const half8 (&a)[4], const half8 (&bfr)[4],
                                        floatx4 (&acc)[8][4]) {
    __builtin_amdgcn_s_setprio(1);
    #pragma unroll
    for (int mi = 0; mi < 4; ++mi)
        #pragma unroll
        for (int ni = 0; ni < 4; ++ni)
            acc[MQ * 4 + mi][ni] = __builtin_amdgcn_mfma_f32_16x16x32_f16(
                a[mi], bfr[ni], acc[MQ * 4 + mi][ni], 0, 0, 0);
    __builtin_amdgcn_s_setprio(0);
}

// One chunk: 24 ds_read_b128, 96 MFMA per wave. Single a-buffer (48-reg
// fragment peak). Per-element order: hi*hi, hi*lo, lo*hi.
__device__ __forceinline__ void chunk_compute(const _Float16* lds, int p,
    int wave_m, int wave_n, int s, int quad, floatx4 (&acc)[8][4])
{
    const _Float16* Ah = lds + (p * 4 + 0) * 8192;
    const _Float16* Al = lds + (p * 4 + 1) * 8192;
    const _Float16* Bh = lds + (p * 4 + 2) * 8192;
    const _Float16* Bl = lds + (p * 4 + 3) * 8192;
    half8 bh[4], bl[4], a[4];
    ds_load_b(Bh, wave_n, s, quad, bh);
    ds_load_b(Bl, wave_n, s, quad, bl);
    ds_load_a<0>(Ah, wave_m, s, quad, a);
    do_mfma<0>(a, bh, acc);           // mq0: hi*hi
    do_mfma<0>(a, bl, acc);           // mq0: hi*lo
    ds_load_a<1>(Ah, wave_m, s, quad, a);
    do_mfma<1>(a, bh, acc);           // mq1: hi*hi
    do_mfma<1>(a, bl, acc);           // mq1: hi*lo
    ds_load_a<0>(Al, wave_m, s, quad, a);
    do_mfma<0>(a, bh, acc);           // mq0: lo*hi
    ds_load_a<1>(Al, wave_m, s, quad, a);
    do_mfma<1>(a, bh, acc);           // mq1: lo*hi
}

__global__ __launch_bounds__(512, 2) void gemm_mfma_kernel(
    const float* __restrict__ Q, const float* __restrict__ K,
    float* __restrict__ out0, unsigned long long* __restrict__ keys_part)
{
    __shared__ __align__(16) _Float16 lds[65536];   // 128 KiB = 8 regions x 16 KB

    const int t      = threadIdx.x;
    const int lane   = t & 63;
    const int wave   = t >> 6;
    const int quad   = lane >> 4;
    const int s      = lane & 15;
    const int wave_m = wave >> 2;     // 0..1 -> 128 output rows
    const int wave_n = wave & 3;      // 0..3 -> 64 output cols

    // T1: XCD-bijective swizzle.
    const int n    = blockIdx.x;
    const int wgid = (n & 7) * 128 + (n >> 3);
    const int kt   = wgid & 15;
    const int qt   = (wgid >> 4) & 15;
    const int b    = wgid >> 8;

    const float* Qp = Q + (size_t)b * C_ * HW_ + qt * 256;   // panel: [c][256 hw]
    const float* Kp = K + (size_t)b * C_ * HW_ + kt * 256;

    float ra[2][8], rb[2][8];

    // Prologue: stage chunks 0,1 synchronously; issue loads for chunk 2.
    stage_load(Qp, Kp, 0, t, ra, rb);
    cvt_write(lds, 0, t, ra, rb);
    stage_load(Qp, Kp, 32, t, ra, rb);
    cvt_write(lds, 1, t, ra, rb);
    stage_load(Qp, Kp, 64, t, ra, rb);
    LGKM0; BARRIER; SCHEDB;

    floatx4 acc[8][4] = {};

    // Chunks 0..5: compute c; boundary writes chunk c+2 (regs held since
    // previous boundary) and issues loads for c+3.
    #pragma unroll 1
    for (int c = 0; c < 6; ++c) {
        chunk_compute(lds, c & 1, wave_m, wave_n, s, quad, acc);
        LGKM0; BARRIER;                 // all reads of buffer p done
        cvt_write(lds, c & 1, t, ra, rb);   // chunk c+2 -> p
        if (c < 5) stage_load(Qp, Kp, (c + 3) * 32, t, ra, rb);
        LGKM0; BARRIER; SCHEDB;         // writes visible
    }
    // Chunks 6,7: fully staged; LDS read-only from here.
    chunk_compute(lds, 0, wave_m, wave_n, s, quad, acc);
    chunk_compute(lds, 1, wave_m, wave_n, s, quad, acc);

    // ---- Epilogue 1: S_vis corner (C/D layout: col=s, row=quad*4+r) ----
    if (qt < 4 && kt < 4) {
        #pragma unroll
        for (int mi8 = 0; mi8 < 8; ++mi8)
            #pragma unroll
            for (int r = 0; r < 4; ++r) {
                int grow = qt * 256 + wave_m * 128 + mi8 * 16 + quad * 4 + r;
                float* orow = out0 + ((size_t)b * VIS_ + grow) * VIS_ + kt * 256 + wave_n * 64;
                #pragma unroll
                for (int ni = 0; ni < 4; ++ni)
                    orow[ni * 16 + s] = acc[mi8][ni][r];
            }
    }

    // ---- Epilogue 2: fused argmax -> PARTIAL slice (plain stores) ----
    __syncthreads();
    unsigned long long* red = (unsigned long long*)lds;   // [256 rows][4 wave_n]

    #pragma unroll
    for (int mi8 = 0; mi8 < 8; ++mi8) {
        #pragma unroll
        for (int r = 0; r < 4; ++r) {
            float best = acc[mi8][0][r];
            int bcol = wave_n * 64 + s;
            #pragma unroll
            for (int ni = 1; ni < 4; ++ni) {
                float v = acc[mi8][ni][r];
                if (v > best) { best = v; bcol = wave_n * 64 + ni * 16 + s; }
            }
            int gcol = kt * 256 + bcol;
            unsigned long long key = ((unsigned long long)mapf(best) << 32)
                                   | (unsigned)(HW_ - 1 - gcol);
            #pragma unroll
            for (int m = 1; m < 16; m <<= 1) {
                unsigned long long o = __shfl_xor(key, m, 64);
                if (o > key) key = o;
            }
            if (s == 0)
                red[(wave_m * 128 + mi8 * 16 + quad * 4 + r) * 4 + wave_n] = key;
        }
    }
    __syncthreads();
    if (t < 256) {
        const unsigned long long* rr = red + t * 4;
        unsigned long long k0 = rr[0], k1 = rr[1], k2 = rr[2], k3 = rr[3];
        unsigned long long m01 = k0 > k1 ? k0 : k1;
        unsigned long long m23 = k2 > k3 ? k2 : k3;
        unsigned long long m = m01 > m23 ? m01 : m23;
        // slice-major: coalesced store, each slot written exactly once
        keys_part[(size_t)kt * (B_ * HW_) + (size_t)b * HW_ + qt * 256 + t] = m;
    }
}

// ---------------- fp32 fallback path (round-1, known-good) ----------------
#define BT   64
#define BK   32
#define LDP  68

__global__ __launch_bounds__(256) void gemm_argmax_kernel(
    const float* __restrict__ Q, const float* __restrict__ K,
    float* __restrict__ out0, unsigned long long* __restrict__ ws)
{
    __shared__ float As[BK][LDP];
    __shared__ float Bs[BK][LDP];
    __shared__ unsigned long long red[BT][17];

    const int t  = threadIdx.x;
    const int tx = t & 15;
    const int ty = t >> 4;
    const int k0 = blockIdx.x * BT;
    const int q0 = blockIdx.y * BT;
    const int b  = blockIdx.z;

    const float* Qb = Q + (size_t)b * C_ * HW_;
    const float* Kb = K + (size_t)b * C_ * HW_;

    float acc[4][4] = {{0.f},{0.f},{0.f},{0.f}};

    for (int c0 = 0; c0 < C_; c0 += BK) {
        #pragma unroll
        for (int i = 0; i < 2; ++i) {
            int idx = i * 256 + t;
            int row = idx >> 4;
            int col = (idx & 15) * 4;
            const float4 a  = *(const float4*)(Qb + (size_t)(c0 + row) * HW_ + q0 + col);
            const float4 bv = *(const float4*)(Kb + (size_t)(c0 + row) * HW_ + k0 + col);
            *(float4*)(&As[row][col]) = a;
            *(float4*)(&Bs[row][col]) = bv;
        }
        __syncthreads();
        #pragma unroll
        for (int cc = 0; cc < BK; ++cc) {
            const float4 av = *(const float4*)(&As[cc][ty * 4]);
            const float4 bv = *(const float4*)(&Bs[cc][tx * 4]);
            const float a_[4] = {av.x, av.y, av.z, av.w};
            const float b_[4] = {bv.x, bv.y, bv.z, bv.w};
            #pragma unroll
            for (int i = 0; i < 4; ++i)
                #pragma unroll
                for (int j = 0; j < 4; ++j)
                    acc[i][j] = fmaf(a_[i], b_[j], acc[i][j]);
        }
        __syncthreads();
    }

    if (q0 < VIS_ && k0 < VIS_) {
        #pragma unroll
        for (int i = 0; i < 4; ++i) {
            float4 v = make_float4(acc[i][0], acc[i][1], acc[i][2], acc[i][3]);
            size_t off = (size_t)b * VIS_ * VIS_ + (size_t)(q0 + ty * 4 + i) * VIS_ + (k0 + tx * 4);
            *(float4*)(out0 + off) = v;
        }
    }

    #pragma unroll
    for (int i = 0; i < 4; ++i) {
        float best = acc[i][0];
        int   bj   = 0;
        #pragma unroll
        for (int j = 1; j < 4; ++j)
            if (acc[i][j] > best) { best = acc[i][j]; bj = j; }
        int kidx = k0 + tx * 4 + bj;
        unsigned long long key = ((unsigned long long)mapf(best) << 32)
                               | (unsigned)(HW_ - 1 - kidx);
        red[ty * 4 + i][tx] = key;
    }
    __syncthreads();
    if (t < BT) {
        unsigned long long best = red[t][0];
        #pragma unroll
        for (int j = 1; j < 16; ++j) {
            unsigned long long v = red[t][j];
            if (v > best) best = v;
        }
        atomicMax(&ws[(size_t)b * HW_ + q0 + t], best);
    }
}

extern "C" void kernel_launch(void* const* d_in, const int* in_sizes, int n_in,
                              void* d_out, int out_size, void* d_ws, size_t ws_size,
                              hipStream_t stream) {
    const float* Q = (const float*)d_in[0];
    const float* K = (const float*)d_in[1];
    float* out0 = (float*)d_out;
    float* out1 = out0 + (size_t)B_ * VIS_ * VIS_;

    unsigned long long* keys = (unsigned long long*)d_ws;
    const int n = B_ * HW_;
    const size_t part_bytes = (size_t)NKT * n * 8;   // 2 MB partial slices

    if (ws_size >= part_bytes) {
        // Main path: 2 launches, no atomics, no workspace init.
        gemm_mfma_kernel<<<dim3((HW_ / 256) * (HW_ / 256) * B_), 512, 0, stream>>>(Q, K, out0, keys);
        finalize_kernel<<<(n + 255) / 256, 256, 0, stream>>>(keys, out1, n, NKT);
    } else {
        init_ws_kernel<<<(n + 255) / 256, 256, 0, stream>>>(keys, n);
        gemm_argmax_kernel<<<dim3(HW_ / BT, HW_ / BT, B_), 256, 0, stream>>>(Q, K, out0, keys);
        finalize_kernel<<<(n + 255) / 256, 256, 0, stream>>>(keys, out1, n, 1);
    }
}

// Round 12
// 196.441 us; speedup vs baseline: 1.0980x; 1.0397x over previous
//
#include <hip/hip_runtime.h>
#include <stdint.h>

// Problem constants: B=4, C=256, H=W=64 -> HW=4096, vis=1024
#define B_   4
#define C_   256
#define HW_  4096
#define VIS_ 1024
#define NKT  16       // kt slices (HW_/256)

using half8   = __attribute__((ext_vector_type(8))) _Float16;
using floatx4 = __attribute__((ext_vector_type(4))) float;

__device__ __forceinline__ unsigned mapf(float v) {
    unsigned u = __float_as_uint(v);
    return (u & 0x80000000u) ? ~u : (u | 0x80000000u);
}

__global__ void init_ws_kernel(unsigned long long* ws, int n) {
    int i = blockIdx.x * blockDim.x + threadIdx.x;
    if (i < n) ws[i] = 0ull;
}

// Reduce `slices` partial key slices (each n rows) and emit argmax index.
__global__ void finalize_kernel(const unsigned long long* __restrict__ ws,
                                float* __restrict__ out1, int n, int slices) {
    int i = blockIdx.x * blockDim.x + threadIdx.x;
    if (i < n) {
        unsigned long long best = ws[i];
        for (int k = 1; k < slices; ++k) {
            unsigned long long v = ws[(size_t)k * n + i];
            if (v > best) best = v;
        }
        unsigned kinv = (unsigned)(best & 0xFFFFFFFFull);
        out1[i] = (float)(HW_ - 1 - (int)kinv);
    }
}

// ---- FUSED 256x256 dedup-split GEMM, 1024 threads / 16 waves ----
//
// Round-12 theory: every pipe-throughput reduction (DS -33%, bytes -33%,
// barriers -66%, vmcnt depth) left the gemm invariant, while adding a VALU
// chain (r10) slowed it 14%, and occupancy sat at 2 waves/SIMD (116 VGPR +
// 128 AGPR acc = 244 combined) all session. Consistent diagnosis: EXPOSED
// DEPENDENT-OP LATENCY at 2 waves/SIMD, not any pipe's bandwidth. Fix:
// same 256^2 tile with 16 waves (4x4 wave grid, 64x64 out/wave): acc drops
// to 64 AGPR, chunk-live VGPR ~60 -> combined ~124 <= 128 -> 4 waves/SIMD.
// Cost: B-fragment amplification 2->4 (+33% DS read) — acceptable since r7
// proved DS bandwidth is not binding. Numerics: per-element accumulation
// order (hh, hl, lh; ascending chunks) identical to rounds 10/11.
//
// LDS: 8 regions x 16 KB (region = p*4 + {0:Ah,1:Al,2:Bh,3:Bl}, p = c&1).
// Boundary after chunk c: LGKM0+BARRIER (reads of p done) -> load chunk
// c+2 to regs (transient) -> cvt+write into p -> LGKM0+BARRIER.
// Chunk swizzle (involution on 16B chunks within a 64B row):
//   lds chunk (row, ch) holds global k-chunk ch ^ ((row>>1)&3)

#define BARRIER __builtin_amdgcn_s_barrier()
#define LGKM0   asm volatile("s_waitcnt lgkmcnt(0)" ::: "memory")
#define SCHEDB  __builtin_amdgcn_sched_barrier(0)

// 8 dwords per side per thread: hw = t&255, oct o = t>>8 (0..3).
__device__ __forceinline__ void stage_load(const float* __restrict__ Qp,
                                           const float* __restrict__ Kp,
                                           int kb, int t,
                                           float (&ra)[8], float (&rb)[8])
{
    const int hw = t & 255, o = t >> 8;
    const int c0 = kb + o * 8;
    const float* qa = Qp + (size_t)c0 * HW_ + hw;
    const float* ka = Kp + (size_t)c0 * HW_ + hw;
    #pragma unroll
    for (int j = 0; j < 8; ++j) {
        ra[j] = qa[(size_t)j * HW_];
        rb[j] = ka[(size_t)j * HW_];
    }
}

// Convert to hi/lo f16 and write one half8 per region (swizzled).
__device__ __forceinline__ void cvt_write(_Float16* lds, int p, int t,
                                          const float (&ra)[8],
                                          const float (&rb)[8])
{
    _Float16* Ah = lds + (p * 4 + 0) * 8192;
    _Float16* Al = lds + (p * 4 + 1) * 8192;
    _Float16* Bh = lds + (p * 4 + 2) * 8192;
    _Float16* Bl = lds + (p * 4 + 3) * 8192;
    const int hw = t & 255, o = t >> 8;
    const int ch = o ^ ((hw >> 1) & 3);
    half8 ha, la, hb, lb;
    #pragma unroll
    for (int j = 0; j < 8; ++j) {
        float v = ra[j];
        _Float16 h = (_Float16)v;
        ha[j] = h; la[j] = (_Float16)(v - (float)h);
        float w = rb[j];
        _Float16 g = (_Float16)w;
        hb[j] = g; lb[j] = (_Float16)(w - (float)g);
    }
    *(half8*)(Ah + hw * 32 + ch * 8) = ha;
    *(half8*)(Al + hw * 32 + ch * 8) = la;
    *(half8*)(Bh + hw * 32 + ch * 8) = hb;
    *(half8*)(Bl + hw * 32 + ch * 8) = lb;
}

__device__ __forceinline__ void ds_load_a(const _Float16* base, int wm, int s,
                                          int quad, half8 (&a)[4]) {
    #pragma unroll
    for (int mi = 0; mi < 4; ++mi) {
        int row = wm * 64 + mi * 16 + s;
        int ch  = quad ^ ((row >> 1) & 3);
        a[mi] = *(const half8*)(base + row * 32 + ch * 8);
    }
}

__device__ __forceinline__ void ds_load_b(const _Float16* base, int wn, int s,
                                          int quad, half8 (&bfr)[4]) {
    #pragma unroll
    for (int ni = 0; ni < 4; ++ni) {
        int col = wn * 64 + ni * 16 + s;
        int ch  = quad ^ ((col >> 1) & 3);
        bfr[ni] = *(const half8*)(base + col * 32 + ch * 8);
    }
}

__device__ __forceinline__ void do_mfma(const half8 (&a)[4], const half8 (&bfr)[4],
                                        floatx4 (&acc)[4][4]) {
    __builtin_amdgcn_s_setprio(1);
    #pragma unroll
    for (int mi = 0; mi < 4; ++mi)
        #pragma unroll
        for (int ni = 0; ni < 4; ++ni)
            acc[mi][ni] = __builtin_amdgcn_mfma_f32_16x16x32_f16(
                a[mi], bfr[ni], acc[mi][ni], 0, 0, 0);
    __builtin_amdgcn_s_setprio(0);
}

// One chunk per wave: 16 ds_read_b128, 48 MFMA (64x64 out).
// Per-element order: hi*hi, hi*lo, lo*hi — identical to rounds 10/11.
__device__ __forceinline__ void chunk_compute(const _Float16* lds, int p,
    int wm, int wn, int s, int quad, floatx4 (&acc)[4][4])
{
    const _Float16* Ah = lds + (p * 4 + 0) * 8192;
    const _Float16* Al = lds + (p * 4 + 1) * 8192;
    const _Float16* Bh = lds + (p * 4 + 2) * 8192;
    const _Float16* Bl = lds + (p * 4 + 3) * 8192;
    half8 bh[4], bl[4], a[4];
    ds_load_b(Bh, wn, s, quad, bh);
    ds_load_b(Bl, wn, s, quad, bl);
    ds_load_a(Ah, wm, s, quad, a);
    do_mfma(a, bh, acc);              // hi*hi
    do_mfma(a, bl, acc);              // hi*lo
    ds_load_a(Al, wm, s, quad, a);
    do_mfma(a, bh, acc);              // lo*hi
}

__global__ __launch_bounds__(1024, 1) void gemm_mfma_kernel(
    const float* __restrict__ Q, const float* __restrict__ K,
    float* __restrict__ out0, unsigned long long* __restrict__ keys_part)
{
    __shared__ __align__(16) _Float16 lds[65536];   // 128 KiB = 8 regions x 16 KB

    const int t    = threadIdx.x;
    const int lane = t & 63;
    const int wave = t >> 6;          // 0..15
    const int quad = lane >> 4;
    const int s    = lane & 15;
    const int wm   = wave >> 2;       // 0..3 -> 64 output rows
    const int wn   = wave & 3;        // 0..3 -> 64 output cols

    // T1: XCD-bijective swizzle.
    const int n    = blockIdx.x;
    const int wgid = (n & 7) * 128 + (n >> 3);
    const int kt   = wgid & 15;
    const int qt   = (wgid >> 4) & 15;
    const int b    = wgid >> 8;

    const float* Qp = Q + (size_t)b * C_ * HW_ + qt * 256;   // panel: [c][256 hw]
    const float* Kp = K + (size_t)b * C_ * HW_ + kt * 256;

    float ra[8], rb[8];

    // Prologue: stage chunks 0 (buf0) and 1 (buf1).
    stage_load(Qp, Kp, 0, t, ra, rb);
    cvt_write(lds, 0, t, ra, rb);
    stage_load(Qp, Kp, 32, t, ra, rb);
    cvt_write(lds, 1, t, ra, rb);
    LGKM0; BARRIER; SCHEDB;

    floatx4 acc[4][4] = {};

    // Chunks 0..5: compute c; boundary stages chunk c+2 into c's buffer.
    #pragma unroll 1
    for (int c = 0; c < 6; ++c) {
        chunk_compute(lds, c & 1, wm, wn, s, quad, acc);
        LGKM0; BARRIER;                       // all reads of buffer p done
        stage_load(Qp, Kp, (c + 2) * 32, t, ra, rb);
        cvt_write(lds, c & 1, t, ra, rb);     // chunk c+2 -> p
        LGKM0; BARRIER; SCHEDB;               // writes visible
    }
    // Chunks 6,7: fully staged; LDS read-only from here.
    chunk_compute(lds, 0, wm, wn, s, quad, acc);
    chunk_compute(lds, 1, wm, wn, s, quad, acc);

    // ---- Epilogue 1: S_vis corner (C/D layout: col=s, row=quad*4+r) ----
    if (qt < 4 && kt < 4) {
        #pragma unroll
        for (int mi = 0; mi < 4; ++mi)
            #pragma unroll
            for (int r = 0; r < 4; ++r) {
                int grow = qt * 256 + wm * 64 + mi * 16 + quad * 4 + r;
                float* orow = out0 + ((size_t)b * VIS_ + grow) * VIS_ + kt * 256 + wn * 64;
                #pragma unroll
                for (int ni = 0; ni < 4; ++ni)
                    orow[ni * 16 + s] = acc[mi][ni][r];
            }
    }

    // ---- Epilogue 2: fused argmax -> PARTIAL slice (plain stores) ----
    __syncthreads();
    unsigned long long* red = (unsigned long long*)lds;   // [256 rows][4 wn]

    #pragma unroll
    for (int mi = 0; mi < 4; ++mi) {
        #pragma unroll
        for (int r = 0; r < 4; ++r) {
            float best = acc[mi][0][r];
            int bcol = wn * 64 + s;
            #pragma unroll
            for (int ni = 1; ni < 4; ++ni) {
                float v = acc[mi][ni][r];
                if (v > best) { best = v; bcol = wn * 64 + ni * 16 + s; }
            }
            int gcol = kt * 256 + bcol;
            unsigned long long key = ((unsigned long long)mapf(best) << 32)
                                   | (unsigned)(HW_ - 1 - gcol);
            #pragma unroll
            for (int m = 1; m < 16; m <<= 1) {
                unsigned long long o = __shfl_xor(key, m, 64);
                if (o > key) key = o;
            }
            if (s == 0)
                red[(wm * 64 + mi * 16 + quad * 4 + r) * 4 + wn] = key;
        }
    }
    __syncthreads();
    if (t < 256) {
        const unsigned long long* rr = red + t * 4;
        unsigned long long k0 = rr[0], k1 = rr[1], k2 = rr[2], k3 = rr[3];
        unsigned long long m01 = k0 > k1 ? k0 : k1;
        unsigned long long m23 = k2 > k3 ? k2 : k3;
        unsigned long long m = m01 > m23 ? m01 : m23;
        keys_part[(size_t)kt * (B_ * HW_) + (size_t)b * HW_ + qt * 256 + t] = m;
    }
}

// ---------------- fp32 fallback path (round-1, known-good) ----------------
#define BT   64
#define BK   32
#define LDP  68

__global__ __launch_bounds__(256) void gemm_argmax_kernel(
    const float* __restrict__ Q, const float* __restrict__ K,
    float* __restrict__ out0, unsigned long long* __restrict__ ws)
{
    __shared__ float As[BK][LDP];
    __shared__ float Bs[BK][LDP];
    __shared__ unsigned long long red[BT][17];

    const int t  = threadIdx.x;
    const int tx = t & 15;
    const int ty = t >> 4;
    const int k0 = blockIdx.x * BT;
    const int q0 = blockIdx.y * BT;
    const int b  = blockIdx.z;

    const float* Qb = Q + (size_t)b * C_ * HW_;
    const float* Kb = K + (size_t)b * C_ * HW_;

    float acc[4][4] = {{0.f},{0.f},{0.f},{0.f}};

    for (int c0 = 0; c0 < C_; c0 += BK) {
        #pragma unroll
        for (int i = 0; i < 2; ++i) {
            int idx = i * 256 + t;
            int row = idx >> 4;
            int col = (idx & 15) * 4;
            const float4 a  = *(const float4*)(Qb + (size_t)(c0 + row) * HW_ + q0 + col);
            const float4 bv = *(const float4*)(Kb + (size_t)(c0 + row) * HW_ + k0 + col);
            *(float4*)(&As[row][col]) = a;
            *(float4*)(&Bs[row][col]) = bv;
        }
        __syncthreads();
        #pragma unroll
        for (int cc = 0; cc < BK; ++cc) {
            const float4 av = *(const float4*)(&As[cc][ty * 4]);
            const float4 bv = *(const float4*)(&Bs[cc][tx * 4]);
            const float a_[4] = {av.x, av.y, av.z, av.w};
            const float b_[4] = {bv.x, bv.y, bv.z, bv.w};
            #pragma unroll
            for (int i = 0; i < 4; ++i)
                #pragma unroll
                for (int j = 0; j < 4; ++j)
                    acc[i][j] = fmaf(a_[i], b_[j], acc[i][j]);
        }
        __syncthreads();
    }

    if (q0 < VIS_ && k0 < VIS_) {
        #pragma unroll
        for (int i = 0; i < 4; ++i) {
            float4 v = make_float4(acc[i][0], acc[i][1], acc[i][2], acc[i][3]);
            size_t off = (size_t)b * VIS_ * VIS_ + (size_t)(q0 + ty * 4 + i) * VIS_ + (k0 + tx * 4);
            *(float4*)(out0 + off) = v;
        }
    }

    #pragma unroll
    for (int i = 0; i < 4; ++i) {
        float best = acc[i][0];
        int   bj   = 0;
        #pragma unroll
        for (int j = 1; j < 4; ++j)
            if (acc[i][j] > best) { best = acc[i][j]; bj = j; }
        int kidx = k0 + tx * 4 + bj;
        unsigned long long key = ((unsigned long long)mapf(best) << 32)
                               | (unsigned)(HW_ - 1 - kidx);
        red[ty * 4 + i][tx] = key;
    }
    __syncthreads();
    if (t < BT) {
        unsigned long long best = red[t][0];
        #pragma unroll
        for (int j = 1; j < 16; ++j) {
            unsigned long long v = red[t][j];
            if (v > best) best = v;
        }
        atomicMax(&ws[(size_t)b * HW_ + q0 + t], best);
    }
}

extern "C" void kernel_launch(void* const* d_in, const int* in_sizes, int n_in,
                              void* d_out, int out_size, void* d_ws, size_t ws_size,
                              hipStream_t stream) {
    const float* Q = (const float*)d_in[0];
    const float* K = (const float*)d_in[1];
    float* out0 = (float*)d_out;
    float* out1 = out0 + (size_t)B_ * VIS_ * VIS_;

    unsigned long long* keys = (unsigned long long*)d_ws;
    const int n = B_ * HW_;
    const size_t part_bytes = (size_t)NKT * n * 8;   // 2 MB partial slices

    if (ws_size >= part_bytes) {
        // Main path: 2 launches, no atomics, no workspace init.
        gemm_mfma_kernel<<<dim3((HW_ / 256) * (HW_ / 256) * B_), 1024, 0, stream>>>(Q, K, out0, keys);
        finalize_kernel<<<(n + 255) / 256, 256, 0, stream>>>(keys, out1, n, NKT);
    } else {
        init_ws_kernel<<<(n + 255) / 256, 256, 0, stream>>>(keys, n);
        gemm_argmax_kernel<<<dim3(HW_ / BT, HW_ / BT, B_), 256, 0, stream>>>(Q, K, out0, keys);
        finalize_kernel<<<(n + 255) / 256, 256, 0, stream>>>(keys, out1, n, 1);
    }
}